// Round 5
// baseline (1300.694 us; speedup 1.0000x reference)
//
#include <hip/hip_runtime.h>
#include <math.h>

#define EPSBN 1e-3f

typedef unsigned long long ull;
typedef unsigned short u16;
typedef __attribute__((ext_vector_type(8))) short bf16x8;
typedef __attribute__((ext_vector_type(4))) float f32x4;

// ---------------- workspace layout (float offsets) ----------------
#define WS_W1F 0        // 480   conv1 w (BN1 folded)
#define WS_B1F 480      // 16
#define WS_B2F 496      // 32
#define WS_W2F 528      // 3072  conv2 w (BN2 folded) -> 3600
#define WS_BL1 3600     // 128   lstm1 bias (BN3 folded)
#define WS_BL2 3728     // 96
#define WS_BL3 3824     // 64 -> 3888
#define WS_B1P 3888     // 8192 u16 (bf16 B-frags L1, gate-major tiles) -> 7984
#define WS_B2P 7984     // 6144 u16 -> 11056
#define WS_B3P 11056    // 4096 u16 -> 13104
#define WS_R2  13104    // r2 bf16, rows*505*32

__device__ __forceinline__ u16 f2b(float f) {
  unsigned u = __float_as_uint(f);
  return (u16)((u + 0x7FFFu + ((u >> 16) & 1u)) >> 16);  // RNE
}
// rcp-based activations: v_exp + v_rcp, no IEEE-divide sequences
__device__ __forceinline__ float sigm(float v)  { return __builtin_amdgcn_rcpf(1.f + __expf(-v)); }
__device__ __forceinline__ float tanh_(float v) { return fmaf(2.f, __builtin_amdgcn_rcpf(1.f + __expf(-2.f * v)), -1.f); }

// ---------------- prep ----------------
__global__ __launch_bounds__(256) void prep_kernel(
    const float* __restrict__ bn1g, const float* __restrict__ bn1b,
    const float* __restrict__ bn1m, const float* __restrict__ bn1v,
    const float* __restrict__ bn2g, const float* __restrict__ bn2b,
    const float* __restrict__ bn2m, const float* __restrict__ bn2v,
    const float* __restrict__ bn3g, const float* __restrict__ bn3b,
    const float* __restrict__ bn3m, const float* __restrict__ bn3v,
    const float* __restrict__ c1w, const float* __restrict__ c1b,
    const float* __restrict__ c2w, const float* __restrict__ c2b,
    const float* __restrict__ l1W, const float* __restrict__ l1U, const float* __restrict__ l1b,
    const float* __restrict__ l2W, const float* __restrict__ l2U, const float* __restrict__ l2b,
    const float* __restrict__ l3W, const float* __restrict__ l3U, const float* __restrict__ l3b,
    float* __restrict__ ws)
{
  __shared__ float s1[10], t1[10], s2[16], t2[16], s3[32], t3[32];
  int tid = threadIdx.x;
  if (tid < 10)                  { float s = bn1g[tid] * rsqrtf(bn1v[tid] + EPSBN); s1[tid] = s; t1[tid] = bn1b[tid] - bn1m[tid] * s; }
  else if (tid >= 32 && tid < 48){ int c = tid - 32; float s = bn2g[c] * rsqrtf(bn2v[c] + EPSBN); s2[c] = s; t2[c] = bn2b[c] - bn2m[c] * s; }
  else if (tid >= 64 && tid < 96){ int c = tid - 64; float s = bn3g[c] * rsqrtf(bn3v[c] + EPSBN); s3[c] = s; t3[c] = bn3b[c] - bn3m[c] * s; }
  __syncthreads();

  float* w1f = ws + WS_W1F;
  float* b1f = ws + WS_B1F;
  float* b2f = ws + WS_B2F;
  float* w2f = ws + WS_W2F;
  float* bL1 = ws + WS_BL1;
  float* bL2 = ws + WS_BL2;
  float* bL3 = ws + WS_BL3;
  u16* B1P = (u16*)(ws + WS_B1P);
  u16* B2P = (u16*)(ws + WS_B2P);
  u16* B3P = (u16*)(ws + WS_B3P);

  for (int i = tid; i < 480; i += 256) { int ci = (i >> 4) % 10; w1f[i] = c1w[i] * s1[ci]; }
  for (int co = tid; co < 16; co += 256) {
    float a = c1b[co];
    for (int k = 0; k < 3; k++) for (int ci = 0; ci < 10; ci++) a += t1[ci] * c1w[(k * 10 + ci) * 16 + co];
    b1f[co] = a;
  }
  for (int i = tid; i < 3072; i += 256) { int ci = (i >> 5) & 15; w2f[i] = c2w[i] * s2[ci]; }
  for (int co = tid; co < 32; co += 256) {
    float a = c2b[co];
    for (int k = 0; k < 6; k++) for (int ci = 0; ci < 16; ci++) a += t2[ci] * c2w[(k * 16 + ci) * 32 + co];
    b2f[co] = a;
  }
  for (int j = tid; j < 128; j += 256) {
    float a = l1b[j];
    for (int k = 0; k < 32; k++) a += t3[k] * l1W[k * 128 + j];
    bL1[j] = a;
  }
  for (int j = tid; j < 96; j += 256) bL2[j] = l2b[j];
  for (int j = tid; j < 64; j += 256) bL3[j] = l3b[j];

  // L1: gate-major tiles. tile nt = uh*4 + g holds col j = g*32 + uh*16 + r16.
  for (int i = tid; i < 2 * 8 * 64 * 8; i += 256) {
    int e = i & 7, l = (i >> 3) & 63, nt = (i >> 9) & 7, kt = i >> 12;
    int g = nt & 3, uh = nt >> 2;
    int j = g * 32 + uh * 16 + (l & 15);
    int k = kt * 32 + ((l >> 4) << 3) + e;
    float v = (k < 32) ? l1W[k * 128 + j] * s3[k] : l1U[(k - 32) * 128 + j];
    B1P[i] = f2b(v);
  }
  // L2: natural tiles (col = nt*16 + r16), z goes through wave-local LDS
  for (int i = tid; i < 2 * 6 * 64 * 8; i += 256) {
    int e = i & 7, l = (i >> 3) & 63, m = i >> 9;
    int nt = m % 6, kt = m / 6;
    int j = nt * 16 + (l & 15);
    int k = kt * 32 + ((l >> 4) << 3) + e;
    float v = (k < 32) ? l2W[k * 96 + j] : ((k < 56) ? l2U[(k - 32) * 96 + j] : 0.f);
    B2P[i] = f2b(v);
  }
  // L3: tiles are already gate-major (H=16): tile g holds col g*16 + r16
  for (int i = tid; i < 2 * 4 * 64 * 8; i += 256) {
    int e = i & 7, l = (i >> 3) & 63, m = i >> 9;
    int nt = m & 3, kt = m >> 2;
    int j = nt * 16 + (l & 15);
    int k = kt * 32 + ((l >> 4) << 3) + e;
    float v = (k < 24) ? l3W[k * 64 + j] : ((k < 40) ? l3U[(k - 24) * 64 + j] : 0.f);
    B3P[i] = f2b(v);
  }
}

// ---------------- fused conv1+ReLU+conv2+ReLU, bf16 out, 4 rows/block ----------------
#define CT 128
__global__ __launch_bounds__(256, 4) void conv_kernel(
    const float* __restrict__ x, const float* __restrict__ ws,
    u16* __restrict__ r2, int row0)
{
  int t0 = blockIdx.x * CT;
  int n2 = min(CT, 505 - t0);
  int n1 = n2 + 5;
  int nx = n1 + 2;
  int tid = threadIdx.x;

  __shared__ float xs[135 * 10];
  __shared__ float r1s[133 * 17];
  __shared__ float w1f[480];
  __shared__ float b1f[16];
  alignas(16) __shared__ float w2f[3072];
  __shared__ float b2f[32];

  for (int i = tid; i < 480;  i += 256) w1f[i] = ws[WS_W1F + i];
  for (int i = tid; i < 16;   i += 256) b1f[i] = ws[WS_B1F + i];
  for (int i = tid; i < 32;   i += 256) b2f[i] = ws[WS_B2F + i];
  for (int i = tid; i < 3072; i += 256) w2f[i] = ws[WS_W2F + i];

  int cog = (tid & 7) * 4;
  int tg  = (tid >> 3) * 4;

  for (int rr = 0; rr < 4; rr++) {
    int bl = blockIdx.y * 4 + rr;      // local row within chunk
    __syncthreads();                   // protect xs/r1s from previous readers + weight staging
    const float* xb = x + ((size_t)(row0 + bl) * 512 + t0) * 10;
    for (int i = tid; i < nx * 10; i += 256) xs[i] = xb[i];
    __syncthreads();

    #pragma unroll 1
    for (int i = tid; i < n1 * 16; i += 256) {
      int tt = i >> 4, c = i & 15;
      float a = b1f[c];
      #pragma unroll
      for (int k = 0; k < 3; k++)
        #pragma unroll
        for (int ci = 0; ci < 10; ci++)
          a = fmaf(xs[(tt + k) * 10 + ci], w1f[(k * 10 + ci) * 16 + c], a);
      r1s[tt * 17 + c] = fmaxf(a, 0.f);
    }
    __syncthreads();

    float acc[4][4];
    #pragma unroll
    for (int i2 = 0; i2 < 4; i2++)
      #pragma unroll
      for (int j2 = 0; j2 < 4; j2++) acc[i2][j2] = b2f[cog + j2];
    #pragma unroll 4
    for (int kc = 0; kc < 96; kc++) {
      int k2 = kc >> 4;
      float4 w4 = *(const float4*)&w2f[kc * 32 + cog];
      #pragma unroll
      for (int i2 = 0; i2 < 4; i2++) {
        float xv = r1s[(tg + i2 + k2) * 17 + (kc & 15)];
        acc[i2][0] = fmaf(xv, w4.x, acc[i2][0]);
        acc[i2][1] = fmaf(xv, w4.y, acc[i2][1]);
        acc[i2][2] = fmaf(xv, w4.z, acc[i2][2]);
        acc[i2][3] = fmaf(xv, w4.w, acc[i2][3]);
      }
    }
    #pragma unroll
    for (int i2 = 0; i2 < 4; i2++) {
      int tt = tg + i2;
      if (tt < n2) {
        ull o = (ull)f2b(fmaxf(acc[i2][0], 0.f))
              | ((ull)f2b(fmaxf(acc[i2][1], 0.f)) << 16)
              | ((ull)f2b(fmaxf(acc[i2][2], 0.f)) << 32)
              | ((ull)f2b(fmaxf(acc[i2][3], 0.f)) << 48);
        *(ull*)&r2[((size_t)bl * 505 + (t0 + tt)) * 32 + cog] = o;
      }
    }
  }
}

// ---------------- LSTM: lane-local gates, ping-pong xh, 1 barrier/iter ----------------
// iter i: L1@t=i (waves 0,1), L2@t=i-1 (wave 2, wave-local z LDS), L3@t=i-2 (wave 3)
// all xh reads from [p], all writes to [p^1] -> single end barrier suffices.
#define SWZ(row, byte) ((byte) ^ (((row) & 7) << 4))
#define MFMA(a, b, c) __builtin_amdgcn_mfma_f32_16x16x32_bf16((a), (b), (c), 0, 0, 0)

__global__ __launch_bounds__(256, 5) void lstm_kernel(
    const u16* __restrict__ r2, const float* __restrict__ ws,
    const float* __restrict__ d1w, const float* __restrict__ d1b,
    const float* __restrict__ outw, const float* __restrict__ outb,
    float* __restrict__ out, int row0)
{
  int tid = threadIdx.x;
  int l   = tid & 63;
  int w   = tid >> 6;
  int r16 = l & 15;
  int g   = l >> 4;
  int rl  = blockIdx.x * 4;            // 4 batch rows per block

  alignas(16) __shared__ u16 xh1[2][16 * 64];  // [row][k]: k0-31 x_t, 32-63 h1 (rows 4-15 zero)
  alignas(16) __shared__ u16 xh2[2][16 * 64];  // k0-31 h1_t, 32-55 h2
  alignas(16) __shared__ u16 xh3[2][16 * 64];  // k0-23 h2_t, 24-39 h3
  alignas(16) __shared__ float zb[96 * 4];     // L2 z: [col][q], wave2-private
  __shared__ float hstash[4 * 16];

  const u16* B1P = (const u16*)(ws + WS_B1P);
  const u16* B2P = (const u16*)(ws + WS_B2P);
  const u16* B3P = (const u16*)(ws + WS_B3P);

  // ---- B-fragments -> VGPRs (uniform 6-slot array; NJ per wave)
  bf16x8 F[6][2];
  float bias[6];
  if (w < 2) {
    #pragma unroll
    for (int g4 = 0; g4 < 4; g4++) {
      F[g4][0] = *(const bf16x8*)&B1P[((0 * 8 + w * 4 + g4) * 64 + l) * 8];
      F[g4][1] = *(const bf16x8*)&B1P[((1 * 8 + w * 4 + g4) * 64 + l) * 8];
      bias[g4] = ws[WS_BL1 + g4 * 32 + w * 16 + r16];
    }
    bias[4] = bias[5] = 0.f; F[4][0] = F[4][1] = F[5][0] = F[5][1] = (bf16x8)0;
  } else if (w == 2) {
    #pragma unroll
    for (int j = 0; j < 6; j++) {
      F[j][0] = *(const bf16x8*)&B2P[((0 * 6 + j) * 64 + l) * 8];
      F[j][1] = *(const bf16x8*)&B2P[((1 * 6 + j) * 64 + l) * 8];
      bias[j] = ws[WS_BL2 + j * 16 + r16];
    }
  } else {
    #pragma unroll
    for (int g4 = 0; g4 < 4; g4++) {
      F[g4][0] = *(const bf16x8*)&B3P[((0 * 4 + g4) * 64 + l) * 8];
      F[g4][1] = *(const bf16x8*)&B3P[((1 * 4 + g4) * 64 + l) * 8];
      bias[g4] = ws[WS_BL3 + g4 * 16 + r16];
    }
    bias[4] = bias[5] = 0.f; F[4][0] = F[4][1] = F[5][0] = F[5][1] = (bf16x8)0;
  }

  // cell registers
  float cA[4] = {0.f, 0.f, 0.f, 0.f};   // w0/w1: c1 rows 0-3 (lane r16 = unit); w3: c3
  float c2A = 0.f, c2B = 0.f;           // w2 U-threads
  int tid2 = tid - 128;                  // w2 lane index 0..63
  int r2A = tid2 / 24, u2A = tid2 - r2A * 24;          // sets 0..63
  int s2B = tid2 + 64, r2B = s2B / 24, u2B = s2B - r2B * 24;  // sets 64..95 (tid2<32)

  // x stagers: wave3 lanes 16-47
  bool stager = (w == 3 && l >= 16 && l < 48);
  int slot = l - 16;
  int xrow = slot >> 3, xch = slot & 7;
  const u16* xp = r2 + ((size_t)(rl + xrow) * 505) * 32 + xch * 4;
  ull xreg = 0;

  for (int i = tid; i < 16 * 64; i += 256) {
    xh1[0][i] = 0; xh1[1][i] = 0; xh2[0][i] = 0; xh2[1][i] = 0; xh3[0][i] = 0; xh3[1][i] = 0;
  }
  __syncthreads();
  if (stager) {
    ull x0 = *(const ull*)xp;                                        // x(0)
    *(ull*)((char*)xh1[0] + SWZ(xrow, xrow * 128 + xch * 8)) = x0;
    xreg = *(const ull*)(xp + 32);                                   // x(1)
  }
  __syncthreads();

  #pragma unroll 1
  for (int i = 0; i < 507; ++i) {
    int p = i & 1;
    u16* x1n = xh1[p ^ 1]; u16* x2n = xh2[p ^ 1]; u16* x3n = xh3[p ^ 1];

    if (w < 2) {
      // ---------- L1 (t=i): gates lane-local
      const char* xc = (const char*)xh1[p];
      bf16x8 A0 = *(const bf16x8*)(xc + SWZ(r16, r16 * 128 + g * 16));
      bf16x8 A1 = *(const bf16x8*)(xc + SWZ(r16, r16 * 128 + 64 + g * 16));
      f32x4 z0 = {bias[0], bias[0], bias[0], bias[0]};
      f32x4 z1 = {bias[1], bias[1], bias[1], bias[1]};
      f32x4 z2 = {bias[2], bias[2], bias[2], bias[2]};
      f32x4 z3 = {bias[3], bias[3], bias[3], bias[3]};
      z0 = MFMA(A0, F[0][0], z0); z0 = MFMA(A1, F[0][1], z0);
      z1 = MFMA(A0, F[1][0], z1); z1 = MFMA(A1, F[1][1], z1);
      z2 = MFMA(A0, F[2][0], z2); z2 = MFMA(A1, F[2][1], z2);
      z3 = MFMA(A0, F[3][0], z3); z3 = MFMA(A1, F[3][1], z3);
      if (g == 0 && i <= 504) {
        int u = w * 16 + r16;
        #pragma unroll
        for (int q = 0; q < 4; q++) {
          float gi = sigm(z0[q]), gf = sigm(z1[q]), gG = tanh_(z2[q]), go = sigm(z3[q]);
          cA[q] = fmaf(gf, cA[q], gi * gG);
          u16 hb = f2b(go * tanh_(cA[q]));
          *(u16*)((char*)x1n + SWZ(q, q * 128 + (32 + u) * 2)) = hb;
          *(u16*)((char*)x2n + SWZ(q, q * 128 + u * 2)) = hb;
        }
      }
    } else if (w == 2) {
      // ---------- L2 (t=i-1): z via wave-local LDS
      const char* xc = (const char*)xh2[p];
      bf16x8 A0 = *(const bf16x8*)(xc + SWZ(r16, r16 * 128 + g * 16));
      bf16x8 A1 = *(const bf16x8*)(xc + SWZ(r16, r16 * 128 + 64 + g * 16));
      {
        f32x4 za = {bias[0], bias[0], bias[0], bias[0]};
        f32x4 zbv = {bias[1], bias[1], bias[1], bias[1]};
        f32x4 zc = {bias[2], bias[2], bias[2], bias[2]};
        za  = MFMA(A0, F[0][0], za);  za  = MFMA(A1, F[0][1], za);
        zbv = MFMA(A0, F[1][0], zbv); zbv = MFMA(A1, F[1][1], zbv);
        zc  = MFMA(A0, F[2][0], zc);  zc  = MFMA(A1, F[2][1], zc);
        if (g == 0) {
          *(f32x4*)&zb[(0 * 16 + r16) * 4] = za;
          *(f32x4*)&zb[(1 * 16 + r16) * 4] = zbv;
          *(f32x4*)&zb[(2 * 16 + r16) * 4] = zc;
        }
        za  = {bias[3], bias[3], bias[3], bias[3]};
        zbv = {bias[4], bias[4], bias[4], bias[4]};
        zc  = {bias[5], bias[5], bias[5], bias[5]};
        za  = MFMA(A0, F[3][0], za);  za  = MFMA(A1, F[3][1], za);
        zbv = MFMA(A0, F[4][0], zbv); zbv = MFMA(A1, F[4][1], zbv);
        zc  = MFMA(A0, F[5][0], zc);  zc  = MFMA(A1, F[5][1], zc);
        if (g == 0) {
          *(f32x4*)&zb[(3 * 16 + r16) * 4] = za;
          *(f32x4*)&zb[(4 * 16 + r16) * 4] = zbv;
          *(f32x4*)&zb[(5 * 16 + r16) * 4] = zc;
        }
      }
      if (i >= 1 && i <= 505) {
        // col = gate*24 + u  (Keras gate order i,f,g,o)
        {
          float zi = zb[(u2A) * 4 + r2A], zf = zb[(24 + u2A) * 4 + r2A];
          float zg = zb[(48 + u2A) * 4 + r2A], zo = zb[(72 + u2A) * 4 + r2A];
          float gi = sigm(zi), gf = sigm(zf), gG = tanh_(zg), go = sigm(zo);
          c2A = fmaf(gf, c2A, gi * gG);
          u16 hb = f2b(go * tanh_(c2A));
          *(u16*)((char*)x2n + SWZ(r2A, r2A * 128 + (32 + u2A) * 2)) = hb;
          *(u16*)((char*)x3n + SWZ(r2A, r2A * 128 + u2A * 2)) = hb;
        }
        if (tid2 < 32) {
          float zi = zb[(u2B) * 4 + r2B], zf = zb[(24 + u2B) * 4 + r2B];
          float zg = zb[(48 + u2B) * 4 + r2B], zo = zb[(72 + u2B) * 4 + r2B];
          float gi = sigm(zi), gf = sigm(zf), gG = tanh_(zg), go = sigm(zo);
          c2B = fmaf(gf, c2B, gi * gG);
          u16 hb = f2b(go * tanh_(c2B));
          *(u16*)((char*)x2n + SWZ(r2B, r2B * 128 + (32 + u2B) * 2)) = hb;
          *(u16*)((char*)x3n + SWZ(r2B, r2B * 128 + u2B * 2)) = hb;
        }
      }
    } else {
      // ---------- L3 (t=i-2): gates lane-local; plus x staging
      const char* xc = (const char*)xh3[p];
      bf16x8 A0 = *(const bf16x8*)(xc + SWZ(r16, r16 * 128 + g * 16));
      bf16x8 A1 = *(const bf16x8*)(xc + SWZ(r16, r16 * 128 + 64 + g * 16));
      f32x4 z0 = {bias[0], bias[0], bias[0], bias[0]};
      f32x4 z1 = {bias[1], bias[1], bias[1], bias[1]};
      f32x4 z2 = {bias[2], bias[2], bias[2], bias[2]};
      f32x4 z3 = {bias[3], bias[3], bias[3], bias[3]};
      z0 = MFMA(A0, F[0][0], z0); z0 = MFMA(A1, F[0][1], z0);
      z1 = MFMA(A0, F[1][0], z1); z1 = MFMA(A1, F[1][1], z1);
      z2 = MFMA(A0, F[2][0], z2); z2 = MFMA(A1, F[2][1], z2);
      z3 = MFMA(A0, F[3][0], z3); z3 = MFMA(A1, F[3][1], z3);
      if (g == 0 && i >= 2) {
        int u = r16;
        #pragma unroll
        for (int q = 0; q < 4; q++) {
          float gi = sigm(z0[q]), gf = sigm(z1[q]), gG = tanh_(z2[q]), go = sigm(z3[q]);
          cA[q] = fmaf(gf, cA[q], gi * gG);
          float h = go * tanh_(cA[q]);
          *(u16*)((char*)x3n + SWZ(q, q * 128 + (24 + u) * 2)) = f2b(h);
          if (i == 506) hstash[q * 16 + u] = h;
        }
      }
      if (stager) {
        *(ull*)((char*)x1n + SWZ(xrow, xrow * 128 + xch * 8)) = xreg;  // x(i+1)
        if (i + 2 <= 504) xreg = *(const ull*)(xp + (size_t)(i + 2) * 32);
      }
    }
    __syncthreads();
  }

  // ---------- dense head: 4 rows
  if (tid < 4) {
    int row = tid;
    float hd[16];
    #pragma unroll
    for (int u = 0; u < 16; u++) hd[u] = hstash[row * 16 + u];
    float aa[8];
    #pragma unroll
    for (int o = 0; o < 8; o++) {
      float acc = d1b[o];
      #pragma unroll
      for (int u = 0; u < 16; u++) acc = fmaf(hd[u], d1w[u * 8 + o], acc);
      aa[o] = fmaxf(acc, 0.f);
    }
    float oo[5]; float mx = -1e30f;
    #pragma unroll
    for (int cc = 0; cc < 5; cc++) {
      float acc = outb[cc];
      #pragma unroll
      for (int o = 0; o < 8; o++) acc = fmaf(aa[o], outw[o * 5 + cc], acc);
      oo[cc] = acc; mx = fmaxf(mx, acc);
    }
    float sum = 0.f;
    #pragma unroll
    for (int cc = 0; cc < 5; cc++) { oo[cc] = __expf(oo[cc] - mx); sum += oo[cc]; }
    float inv = 1.f / sum;
    #pragma unroll
    for (int cc = 0; cc < 5; cc++) out[(size_t)(row0 + rl + row) * 5 + cc] = oo[cc] * inv;
  }
}

// ---------------- launch ----------------
extern "C" void kernel_launch(void* const* d_in, const int* in_sizes, int n_in,
                              void* d_out, int out_size, void* d_ws, size_t ws_size,
                              hipStream_t stream)
{
  const float* x    = (const float*)d_in[0];
  const float* bn1g = (const float*)d_in[1];
  const float* bn1b = (const float*)d_in[2];
  const float* bn1m = (const float*)d_in[3];
  const float* bn1v = (const float*)d_in[4];
  const float* bn2g = (const float*)d_in[5];
  const float* bn2b = (const float*)d_in[6];
  const float* bn2m = (const float*)d_in[7];
  const float* bn2v = (const float*)d_in[8];
  const float* bn3g = (const float*)d_in[9];
  const float* bn3b = (const float*)d_in[10];
  const float* bn3m = (const float*)d_in[11];
  const float* bn3v = (const float*)d_in[12];
  const float* c1w  = (const float*)d_in[13];
  const float* c1b  = (const float*)d_in[14];
  const float* c2w  = (const float*)d_in[15];
  const float* c2b  = (const float*)d_in[16];
  const float* l1W  = (const float*)d_in[17];
  const float* l1U  = (const float*)d_in[18];
  const float* l1b  = (const float*)d_in[19];
  const float* l2W  = (const float*)d_in[20];
  const float* l2U  = (const float*)d_in[21];
  const float* l2b  = (const float*)d_in[22];
  const float* l3W  = (const float*)d_in[23];
  const float* l3U  = (const float*)d_in[24];
  const float* l3b  = (const float*)d_in[25];
  const float* d1w  = (const float*)d_in[26];
  const float* d1b  = (const float*)d_in[27];
  const float* outw = (const float*)d_in[28];
  const float* outb = (const float*)d_in[29];

  float* ws = (float*)d_ws;
  u16* r2 = (u16*)(ws + WS_R2);

  prep_kernel<<<1, 256, 0, stream>>>(bn1g, bn1b, bn1m, bn1v,
                                     bn2g, bn2b, bn2m, bn2v,
                                     bn3g, bn3b, bn3m, bn3v,
                                     c1w, c1b, c2w, c2b,
                                     l1W, l1U, l1b, l2W, l2U, l2b, l3W, l3U, l3b,
                                     ws);

  size_t availB = (ws_size > (size_t)WS_R2 * 4) ? ws_size - (size_t)WS_R2 * 4 : 0;
  int nch = 1;
  while ((size_t)(4096 / nch) * 505 * 32 * 2 > availB && nch < 16) nch <<= 1;
  int rows_pc = 4096 / nch;

  for (int ch = 0; ch < nch; ++ch) {
    int row0 = ch * rows_pc;
    dim3 cgrid(4, rows_pc / 4);
    conv_kernel<<<cgrid, 256, 0, stream>>>(x, ws, r2, row0);
    lstm_kernel<<<rows_pc / 4, 256, 0, stream>>>(r2, ws, d1w, d1b, outw, outb, (float*)d_out, row0);
  }
}

// Round 6
// 1110.687 us; speedup vs baseline: 1.1711x; 1.1711x over previous
//
#include <hip/hip_runtime.h>
#include <math.h>

#define EPSBN 1e-3f

typedef unsigned long long ull;
typedef unsigned short u16;
typedef __attribute__((ext_vector_type(8))) short bf16x8;
typedef __attribute__((ext_vector_type(4))) float f32x4;

// ---------------- workspace layout (float offsets) ----------------
#define WS_W1F 0        // 480   conv1 w (BN1 folded)
#define WS_B1F 480      // 16
#define WS_B2F 496      // 32
#define WS_W2F 528      // 3072  conv2 w (BN2 folded) -> 3600
#define WS_BL1 3600     // 128   lstm1 bias (BN3 folded)
#define WS_BL2 3728     // 96
#define WS_BL3 3824     // 64 -> 3888
#define WS_B1P 3888     // 8192 u16 (bf16 B-frags L1, gate-major tiles) -> 7984
#define WS_B2P 7984     // 6144 u16 -> 11056
#define WS_B3P 11056    // 4096 u16 -> 13104
#define WS_R2  13104    // r2 bf16, rows*505*32

__device__ __forceinline__ u16 f2b(float f) {
  unsigned u = __float_as_uint(f);
  return (u16)((u + 0x7FFFu + ((u >> 16) & 1u)) >> 16);  // RNE
}
// rcp-based activations: v_exp + v_rcp, no IEEE-divide sequences
__device__ __forceinline__ float sigm(float v)  { return __builtin_amdgcn_rcpf(1.f + __expf(-v)); }
__device__ __forceinline__ float tanh_(float v) { return fmaf(2.f, __builtin_amdgcn_rcpf(1.f + __expf(-2.f * v)), -1.f); }

// ---------------- prep ----------------
__global__ __launch_bounds__(256) void prep_kernel(
    const float* __restrict__ bn1g, const float* __restrict__ bn1b,
    const float* __restrict__ bn1m, const float* __restrict__ bn1v,
    const float* __restrict__ bn2g, const float* __restrict__ bn2b,
    const float* __restrict__ bn2m, const float* __restrict__ bn2v,
    const float* __restrict__ bn3g, const float* __restrict__ bn3b,
    const float* __restrict__ bn3m, const float* __restrict__ bn3v,
    const float* __restrict__ c1w, const float* __restrict__ c1b,
    const float* __restrict__ c2w, const float* __restrict__ c2b,
    const float* __restrict__ l1W, const float* __restrict__ l1U, const float* __restrict__ l1b,
    const float* __restrict__ l2W, const float* __restrict__ l2U, const float* __restrict__ l2b,
    const float* __restrict__ l3W, const float* __restrict__ l3U, const float* __restrict__ l3b,
    float* __restrict__ ws)
{
  __shared__ float s1[10], t1[10], s2[16], t2[16], s3[32], t3[32];
  int tid = threadIdx.x;
  if (tid < 10)                  { float s = bn1g[tid] * rsqrtf(bn1v[tid] + EPSBN); s1[tid] = s; t1[tid] = bn1b[tid] - bn1m[tid] * s; }
  else if (tid >= 32 && tid < 48){ int c = tid - 32; float s = bn2g[c] * rsqrtf(bn2v[c] + EPSBN); s2[c] = s; t2[c] = bn2b[c] - bn2m[c] * s; }
  else if (tid >= 64 && tid < 96){ int c = tid - 64; float s = bn3g[c] * rsqrtf(bn3v[c] + EPSBN); s3[c] = s; t3[c] = bn3b[c] - bn3m[c] * s; }
  __syncthreads();

  float* w1f = ws + WS_W1F;
  float* b1f = ws + WS_B1F;
  float* b2f = ws + WS_B2F;
  float* w2f = ws + WS_W2F;
  float* bL1 = ws + WS_BL1;
  float* bL2 = ws + WS_BL2;
  float* bL3 = ws + WS_BL3;
  u16* B1P = (u16*)(ws + WS_B1P);
  u16* B2P = (u16*)(ws + WS_B2P);
  u16* B3P = (u16*)(ws + WS_B3P);

  for (int i = tid; i < 480; i += 256) { int ci = (i >> 4) % 10; w1f[i] = c1w[i] * s1[ci]; }
  for (int co = tid; co < 16; co += 256) {
    float a = c1b[co];
    for (int k = 0; k < 3; k++) for (int ci = 0; ci < 10; ci++) a += t1[ci] * c1w[(k * 10 + ci) * 16 + co];
    b1f[co] = a;
  }
  for (int i = tid; i < 3072; i += 256) { int ci = (i >> 5) & 15; w2f[i] = c2w[i] * s2[ci]; }
  for (int co = tid; co < 32; co += 256) {
    float a = c2b[co];
    for (int k = 0; k < 6; k++) for (int ci = 0; ci < 16; ci++) a += t2[ci] * c2w[(k * 16 + ci) * 32 + co];
    b2f[co] = a;
  }
  for (int j = tid; j < 128; j += 256) {
    float a = l1b[j];
    for (int k = 0; k < 32; k++) a += t3[k] * l1W[k * 128 + j];
    bL1[j] = a;
  }
  for (int j = tid; j < 96; j += 256) bL2[j] = l2b[j];
  for (int j = tid; j < 64; j += 256) bL3[j] = l3b[j];

  // L1: gate-major tiles. tile nt = uh*4 + g holds col j = g*32 + uh*16 + r16.
  for (int i = tid; i < 2 * 8 * 64 * 8; i += 256) {
    int e = i & 7, l = (i >> 3) & 63, nt = (i >> 9) & 7, kt = i >> 12;
    int g = nt & 3, uh = nt >> 2;
    int j = g * 32 + uh * 16 + (l & 15);
    int k = kt * 32 + ((l >> 4) << 3) + e;
    float v = (k < 32) ? l1W[k * 128 + j] * s3[k] : l1U[(k - 32) * 128 + j];
    B1P[i] = f2b(v);
  }
  // L2: natural tiles (col = nt*16 + r16), z goes through wave-local LDS
  for (int i = tid; i < 2 * 6 * 64 * 8; i += 256) {
    int e = i & 7, l = (i >> 3) & 63, m = i >> 9;
    int nt = m % 6, kt = m / 6;
    int j = nt * 16 + (l & 15);
    int k = kt * 32 + ((l >> 4) << 3) + e;
    float v = (k < 32) ? l2W[k * 96 + j] : ((k < 56) ? l2U[(k - 32) * 96 + j] : 0.f);
    B2P[i] = f2b(v);
  }
  // L3: tiles are already gate-major (H=16): tile g holds col g*16 + r16
  for (int i = tid; i < 2 * 4 * 64 * 8; i += 256) {
    int e = i & 7, l = (i >> 3) & 63, m = i >> 9;
    int nt = m & 3, kt = m >> 2;
    int j = nt * 16 + (l & 15);
    int k = kt * 32 + ((l >> 4) << 3) + e;
    float v = (k < 24) ? l3W[k * 64 + j] : ((k < 40) ? l3U[(k - 24) * 64 + j] : 0.f);
    B3P[i] = f2b(v);
  }
}

// ---------------- fused conv1+ReLU+conv2+ReLU, bf16 out, 4 rows/block ----------------
#define CT 128
__global__ __launch_bounds__(256, 4) void conv_kernel(
    const float* __restrict__ x, const float* __restrict__ ws,
    u16* __restrict__ r2, int row0)
{
  int t0 = blockIdx.x * CT;
  int n2 = min(CT, 505 - t0);
  int n1 = n2 + 5;
  int nx = n1 + 2;
  int tid = threadIdx.x;

  __shared__ float xs[135 * 10];
  __shared__ float r1s[133 * 17];
  __shared__ float w1f[480];
  __shared__ float b1f[16];
  alignas(16) __shared__ float w2f[3072];
  __shared__ float b2f[32];

  for (int i = tid; i < 480;  i += 256) w1f[i] = ws[WS_W1F + i];
  for (int i = tid; i < 16;   i += 256) b1f[i] = ws[WS_B1F + i];
  for (int i = tid; i < 32;   i += 256) b2f[i] = ws[WS_B2F + i];
  for (int i = tid; i < 3072; i += 256) w2f[i] = ws[WS_W2F + i];

  int cog = (tid & 7) * 4;
  int tg  = (tid >> 3) * 4;

  for (int rr = 0; rr < 4; rr++) {
    int bl = blockIdx.y * 4 + rr;      // local row within chunk
    __syncthreads();                   // protect xs/r1s from previous readers + weight staging
    const float* xb = x + ((size_t)(row0 + bl) * 512 + t0) * 10;
    for (int i = tid; i < nx * 10; i += 256) xs[i] = xb[i];
    __syncthreads();

    #pragma unroll 1
    for (int i = tid; i < n1 * 16; i += 256) {
      int tt = i >> 4, c = i & 15;
      float a = b1f[c];
      #pragma unroll
      for (int k = 0; k < 3; k++)
        #pragma unroll
        for (int ci = 0; ci < 10; ci++)
          a = fmaf(xs[(tt + k) * 10 + ci], w1f[(k * 10 + ci) * 16 + c], a);
      r1s[tt * 17 + c] = fmaxf(a, 0.f);
    }
    __syncthreads();

    float acc[4][4];
    #pragma unroll
    for (int i2 = 0; i2 < 4; i2++)
      #pragma unroll
      for (int j2 = 0; j2 < 4; j2++) acc[i2][j2] = b2f[cog + j2];
    #pragma unroll 4
    for (int kc = 0; kc < 96; kc++) {
      int k2 = kc >> 4;
      float4 w4 = *(const float4*)&w2f[kc * 32 + cog];
      #pragma unroll
      for (int i2 = 0; i2 < 4; i2++) {
        float xv = r1s[(tg + i2 + k2) * 17 + (kc & 15)];
        acc[i2][0] = fmaf(xv, w4.x, acc[i2][0]);
        acc[i2][1] = fmaf(xv, w4.y, acc[i2][1]);
        acc[i2][2] = fmaf(xv, w4.z, acc[i2][2]);
        acc[i2][3] = fmaf(xv, w4.w, acc[i2][3]);
      }
    }
    #pragma unroll
    for (int i2 = 0; i2 < 4; i2++) {
      int tt = tg + i2;
      if (tt < n2) {
        ull o = (ull)f2b(fmaxf(acc[i2][0], 0.f))
              | ((ull)f2b(fmaxf(acc[i2][1], 0.f)) << 16)
              | ((ull)f2b(fmaxf(acc[i2][2], 0.f)) << 32)
              | ((ull)f2b(fmaxf(acc[i2][3], 0.f)) << 48);
        *(ull*)&r2[((size_t)bl * 505 + (t0 + tt)) * 32 + cog] = o;
      }
    }
  }
}

// ---------------- LSTM: lane-local gates, ping-pong xh, 1 barrier/iter ----------------
// iter i: L1@t=i (waves 0,1), L2@t=i-1 (wave 2, wave-local z LDS), L3@t=i-2 (wave 3)
// all xh reads from [p], all writes to [p^1] -> single end barrier suffices.
// __launch_bounds__(256,4): 128-reg budget. (256,5) spilled the 48-reg weight
// fragments to scratch (round 5: WRITE_SIZE 96KB->34MB, -25% perf).
#define SWZ(row, byte) ((byte) ^ (((row) & 7) << 4))
#define MFMA(a, b, c) __builtin_amdgcn_mfma_f32_16x16x32_bf16((a), (b), (c), 0, 0, 0)

__global__ __launch_bounds__(256, 4) void lstm_kernel(
    const u16* __restrict__ r2, const float* __restrict__ ws,
    const float* __restrict__ d1w, const float* __restrict__ d1b,
    const float* __restrict__ outw, const float* __restrict__ outb,
    float* __restrict__ out, int row0)
{
  int tid = threadIdx.x;
  int l   = tid & 63;
  int w   = tid >> 6;
  int r16 = l & 15;
  int g   = l >> 4;
  int rl  = blockIdx.x * 4;            // 4 batch rows per block

  alignas(16) __shared__ u16 xh1[2][16 * 64];  // [row][k]: k0-31 x_t, 32-63 h1 (rows 4-15 zero)
  alignas(16) __shared__ u16 xh2[2][16 * 64];  // k0-31 h1_t, 32-55 h2
  alignas(16) __shared__ u16 xh3[2][16 * 64];  // k0-23 h2_t, 24-39 h3
  alignas(16) __shared__ float zb[96 * 4];     // L2 z: [col][q], wave2-private
  __shared__ float hstash[4 * 16];

  const u16* B1P = (const u16*)(ws + WS_B1P);
  const u16* B2P = (const u16*)(ws + WS_B2P);
  const u16* B3P = (const u16*)(ws + WS_B3P);

  // ---- B-fragments -> VGPRs (uniform 6-slot array; NJ per wave)
  bf16x8 F[6][2];
  float bias[6];
  if (w < 2) {
    #pragma unroll
    for (int g4 = 0; g4 < 4; g4++) {
      F[g4][0] = *(const bf16x8*)&B1P[((0 * 8 + w * 4 + g4) * 64 + l) * 8];
      F[g4][1] = *(const bf16x8*)&B1P[((1 * 8 + w * 4 + g4) * 64 + l) * 8];
      bias[g4] = ws[WS_BL1 + g4 * 32 + w * 16 + r16];
    }
    bias[4] = bias[5] = 0.f; F[4][0] = F[4][1] = F[5][0] = F[5][1] = (bf16x8)0;
  } else if (w == 2) {
    #pragma unroll
    for (int j = 0; j < 6; j++) {
      F[j][0] = *(const bf16x8*)&B2P[((0 * 6 + j) * 64 + l) * 8];
      F[j][1] = *(const bf16x8*)&B2P[((1 * 6 + j) * 64 + l) * 8];
      bias[j] = ws[WS_BL2 + j * 16 + r16];
    }
  } else {
    #pragma unroll
    for (int g4 = 0; g4 < 4; g4++) {
      F[g4][0] = *(const bf16x8*)&B3P[((0 * 4 + g4) * 64 + l) * 8];
      F[g4][1] = *(const bf16x8*)&B3P[((1 * 4 + g4) * 64 + l) * 8];
      bias[g4] = ws[WS_BL3 + g4 * 16 + r16];
    }
    bias[4] = bias[5] = 0.f; F[4][0] = F[4][1] = F[5][0] = F[5][1] = (bf16x8)0;
  }

  // cell registers
  float cA[4] = {0.f, 0.f, 0.f, 0.f};   // w0/w1: c1 rows 0-3 (lane r16 = unit); w3: c3
  float c2A = 0.f, c2B = 0.f;           // w2 U-threads
  int tid2 = tid - 128;                  // w2 lane index 0..63
  int r2A = tid2 / 24, u2A = tid2 - r2A * 24;          // sets 0..63
  int s2B = tid2 + 64, r2B = s2B / 24, u2B = s2B - r2B * 24;  // sets 64..95 (tid2<32)

  // x stagers: wave3 lanes 16-47
  bool stager = (w == 3 && l >= 16 && l < 48);
  int slot = l - 16;
  int xrow = slot >> 3, xch = slot & 7;
  const u16* xp = r2 + ((size_t)(rl + xrow) * 505) * 32 + xch * 4;
  ull xreg = 0;

  for (int i = tid; i < 16 * 64; i += 256) {
    xh1[0][i] = 0; xh1[1][i] = 0; xh2[0][i] = 0; xh2[1][i] = 0; xh3[0][i] = 0; xh3[1][i] = 0;
  }
  __syncthreads();
  if (stager) {
    ull x0 = *(const ull*)xp;                                        // x(0)
    *(ull*)((char*)xh1[0] + SWZ(xrow, xrow * 128 + xch * 8)) = x0;
    xreg = *(const ull*)(xp + 32);                                   // x(1)
  }
  __syncthreads();

  #pragma unroll 1
  for (int i = 0; i < 507; ++i) {
    int p = i & 1;
    u16* x1n = xh1[p ^ 1]; u16* x2n = xh2[p ^ 1]; u16* x3n = xh3[p ^ 1];

    if (w < 2) {
      // ---------- L1 (t=i): gates lane-local
      const char* xc = (const char*)xh1[p];
      bf16x8 A0 = *(const bf16x8*)(xc + SWZ(r16, r16 * 128 + g * 16));
      bf16x8 A1 = *(const bf16x8*)(xc + SWZ(r16, r16 * 128 + 64 + g * 16));
      f32x4 z0 = {bias[0], bias[0], bias[0], bias[0]};
      f32x4 z1 = {bias[1], bias[1], bias[1], bias[1]};
      f32x4 z2 = {bias[2], bias[2], bias[2], bias[2]};
      f32x4 z3 = {bias[3], bias[3], bias[3], bias[3]};
      z0 = MFMA(A0, F[0][0], z0); z0 = MFMA(A1, F[0][1], z0);
      z1 = MFMA(A0, F[1][0], z1); z1 = MFMA(A1, F[1][1], z1);
      z2 = MFMA(A0, F[2][0], z2); z2 = MFMA(A1, F[2][1], z2);
      z3 = MFMA(A0, F[3][0], z3); z3 = MFMA(A1, F[3][1], z3);
      if (g == 0 && i <= 504) {
        int u = w * 16 + r16;
        #pragma unroll
        for (int q = 0; q < 4; q++) {
          float gi = sigm(z0[q]), gf = sigm(z1[q]), gG = tanh_(z2[q]), go = sigm(z3[q]);
          cA[q] = fmaf(gf, cA[q], gi * gG);
          u16 hb = f2b(go * tanh_(cA[q]));
          *(u16*)((char*)x1n + SWZ(q, q * 128 + (32 + u) * 2)) = hb;
          *(u16*)((char*)x2n + SWZ(q, q * 128 + u * 2)) = hb;
        }
      }
    } else if (w == 2) {
      // ---------- L2 (t=i-1): z via wave-local LDS
      const char* xc = (const char*)xh2[p];
      bf16x8 A0 = *(const bf16x8*)(xc + SWZ(r16, r16 * 128 + g * 16));
      bf16x8 A1 = *(const bf16x8*)(xc + SWZ(r16, r16 * 128 + 64 + g * 16));
      {
        f32x4 za = {bias[0], bias[0], bias[0], bias[0]};
        f32x4 zbv = {bias[1], bias[1], bias[1], bias[1]};
        f32x4 zc = {bias[2], bias[2], bias[2], bias[2]};
        za  = MFMA(A0, F[0][0], za);  za  = MFMA(A1, F[0][1], za);
        zbv = MFMA(A0, F[1][0], zbv); zbv = MFMA(A1, F[1][1], zbv);
        zc  = MFMA(A0, F[2][0], zc);  zc  = MFMA(A1, F[2][1], zc);
        if (g == 0) {
          *(f32x4*)&zb[(0 * 16 + r16) * 4] = za;
          *(f32x4*)&zb[(1 * 16 + r16) * 4] = zbv;
          *(f32x4*)&zb[(2 * 16 + r16) * 4] = zc;
        }
        za  = {bias[3], bias[3], bias[3], bias[3]};
        zbv = {bias[4], bias[4], bias[4], bias[4]};
        zc  = {bias[5], bias[5], bias[5], bias[5]};
        za  = MFMA(A0, F[3][0], za);  za  = MFMA(A1, F[3][1], za);
        zbv = MFMA(A0, F[4][0], zbv); zbv = MFMA(A1, F[4][1], zbv);
        zc  = MFMA(A0, F[5][0], zc);  zc  = MFMA(A1, F[5][1], zc);
        if (g == 0) {
          *(f32x4*)&zb[(3 * 16 + r16) * 4] = za;
          *(f32x4*)&zb[(4 * 16 + r16) * 4] = zbv;
          *(f32x4*)&zb[(5 * 16 + r16) * 4] = zc;
        }
      }
      if (i >= 1 && i <= 505) {
        // col = gate*24 + u  (Keras gate order i,f,g,o)
        {
          float zi = zb[(u2A) * 4 + r2A], zf = zb[(24 + u2A) * 4 + r2A];
          float zg = zb[(48 + u2A) * 4 + r2A], zo = zb[(72 + u2A) * 4 + r2A];
          float gi = sigm(zi), gf = sigm(zf), gG = tanh_(zg), go = sigm(zo);
          c2A = fmaf(gf, c2A, gi * gG);
          u16 hb = f2b(go * tanh_(c2A));
          *(u16*)((char*)x2n + SWZ(r2A, r2A * 128 + (32 + u2A) * 2)) = hb;
          *(u16*)((char*)x3n + SWZ(r2A, r2A * 128 + u2A * 2)) = hb;
        }
        if (tid2 < 32) {
          float zi = zb[(u2B) * 4 + r2B], zf = zb[(24 + u2B) * 4 + r2B];
          float zg = zb[(48 + u2B) * 4 + r2B], zo = zb[(72 + u2B) * 4 + r2B];
          float gi = sigm(zi), gf = sigm(zf), gG = tanh_(zg), go = sigm(zo);
          c2B = fmaf(gf, c2B, gi * gG);
          u16 hb = f2b(go * tanh_(c2B));
          *(u16*)((char*)x2n + SWZ(r2B, r2B * 128 + (32 + u2B) * 2)) = hb;
          *(u16*)((char*)x3n + SWZ(r2B, r2B * 128 + u2B * 2)) = hb;
        }
      }
    } else {
      // ---------- L3 (t=i-2): gates lane-local; plus x staging
      const char* xc = (const char*)xh3[p];
      bf16x8 A0 = *(const bf16x8*)(xc + SWZ(r16, r16 * 128 + g * 16));
      bf16x8 A1 = *(const bf16x8*)(xc + SWZ(r16, r16 * 128 + 64 + g * 16));
      f32x4 z0 = {bias[0], bias[0], bias[0], bias[0]};
      f32x4 z1 = {bias[1], bias[1], bias[1], bias[1]};
      f32x4 z2 = {bias[2], bias[2], bias[2], bias[2]};
      f32x4 z3 = {bias[3], bias[3], bias[3], bias[3]};
      z0 = MFMA(A0, F[0][0], z0); z0 = MFMA(A1, F[0][1], z0);
      z1 = MFMA(A0, F[1][0], z1); z1 = MFMA(A1, F[1][1], z1);
      z2 = MFMA(A0, F[2][0], z2); z2 = MFMA(A1, F[2][1], z2);
      z3 = MFMA(A0, F[3][0], z3); z3 = MFMA(A1, F[3][1], z3);
      if (g == 0 && i >= 2) {
        int u = r16;
        #pragma unroll
        for (int q = 0; q < 4; q++) {
          float gi = sigm(z0[q]), gf = sigm(z1[q]), gG = tanh_(z2[q]), go = sigm(z3[q]);
          cA[q] = fmaf(gf, cA[q], gi * gG);
          float h = go * tanh_(cA[q]);
          *(u16*)((char*)x3n + SWZ(q, q * 128 + (24 + u) * 2)) = f2b(h);
          if (i == 506) hstash[q * 16 + u] = h;
        }
      }
      if (stager) {
        *(ull*)((char*)x1n + SWZ(xrow, xrow * 128 + xch * 8)) = xreg;  // x(i+1)
        if (i + 2 <= 504) xreg = *(const ull*)(xp + (size_t)(i + 2) * 32);
      }
    }
    __syncthreads();
  }

  // ---------- dense head: 4 rows
  if (tid < 4) {
    int row = tid;
    float hd[16];
    #pragma unroll
    for (int u = 0; u < 16; u++) hd[u] = hstash[row * 16 + u];
    float aa[8];
    #pragma unroll
    for (int o = 0; o < 8; o++) {
      float acc = d1b[o];
      #pragma unroll
      for (int u = 0; u < 16; u++) acc = fmaf(hd[u], d1w[u * 8 + o], acc);
      aa[o] = fmaxf(acc, 0.f);
    }
    float oo[5]; float mx = -1e30f;
    #pragma unroll
    for (int cc = 0; cc < 5; cc++) {
      float acc = outb[cc];
      #pragma unroll
      for (int o = 0; o < 8; o++) acc = fmaf(aa[o], outw[o * 5 + cc], acc);
      oo[cc] = acc; mx = fmaxf(mx, acc);
    }
    float sum = 0.f;
    #pragma unroll
    for (int cc = 0; cc < 5; cc++) { oo[cc] = __expf(oo[cc] - mx); sum += oo[cc]; }
    float inv = 1.f / sum;
    #pragma unroll
    for (int cc = 0; cc < 5; cc++) out[(size_t)(row0 + rl + row) * 5 + cc] = oo[cc] * inv;
  }
}

// ---------------- launch ----------------
extern "C" void kernel_launch(void* const* d_in, const int* in_sizes, int n_in,
                              void* d_out, int out_size, void* d_ws, size_t ws_size,
                              hipStream_t stream)
{
  const float* x    = (const float*)d_in[0];
  const float* bn1g = (const float*)d_in[1];
  const float* bn1b = (const float*)d_in[2];
  const float* bn1m = (const float*)d_in[3];
  const float* bn1v = (const float*)d_in[4];
  const float* bn2g = (const float*)d_in[5];
  const float* bn2b = (const float*)d_in[6];
  const float* bn2m = (const float*)d_in[7];
  const float* bn2v = (const float*)d_in[8];
  const float* bn3g = (const float*)d_in[9];
  const float* bn3b = (const float*)d_in[10];
  const float* bn3m = (const float*)d_in[11];
  const float* bn3v = (const float*)d_in[12];
  const float* c1w  = (const float*)d_in[13];
  const float* c1b  = (const float*)d_in[14];
  const float* c2w  = (const float*)d_in[15];
  const float* c2b  = (const float*)d_in[16];
  const float* l1W  = (const float*)d_in[17];
  const float* l1U  = (const float*)d_in[18];
  const float* l1b  = (const float*)d_in[19];
  const float* l2W  = (const float*)d_in[20];
  const float* l2U  = (const float*)d_in[21];
  const float* l2b  = (const float*)d_in[22];
  const float* l3W  = (const float*)d_in[23];
  const float* l3U  = (const float*)d_in[24];
  const float* l3b  = (const float*)d_in[25];
  const float* d1w  = (const float*)d_in[26];
  const float* d1b  = (const float*)d_in[27];
  const float* outw = (const float*)d_in[28];
  const float* outb = (const float*)d_in[29];

  float* ws = (float*)d_ws;
  u16* r2 = (u16*)(ws + WS_R2);

  prep_kernel<<<1, 256, 0, stream>>>(bn1g, bn1b, bn1m, bn1v,
                                     bn2g, bn2b, bn2m, bn2v,
                                     bn3g, bn3b, bn3m, bn3v,
                                     c1w, c1b, c2w, c2b,
                                     l1W, l1U, l1b, l2W, l2U, l2b, l3W, l3U, l3b,
                                     ws);

  size_t availB = (ws_size > (size_t)WS_R2 * 4) ? ws_size - (size_t)WS_R2 * 4 : 0;
  int nch = 1;
  while ((size_t)(4096 / nch) * 505 * 32 * 2 > availB && nch < 16) nch <<= 1;
  int rows_pc = 4096 / nch;

  for (int ch = 0; ch < nch; ++ch) {
    int row0 = ch * rows_pc;
    dim3 cgrid(4, rows_pc / 4);
    conv_kernel<<<cgrid, 256, 0, stream>>>(x, ws, r2, row0);
    lstm_kernel<<<rows_pc / 4, 256, 0, stream>>>(r2, ws, d1w, d1b, outw, outb, (float*)d_out, row0);
  }
}